// Round 1
// 6310.528 us; speedup vs baseline: 1.5988x; 1.5988x over previous
//
#include <hip/hip_runtime.h>
#include <math.h>

#define A_PL 22
#define F_IN_ 16
#define T_LEN 256
#define NBLK_SEQ 64

__device__ __forceinline__ float sigmoidf_(float x) { return 1.f / (1.f + __expf(-x)); }

// Cross-XCD-safe handoff (per-op agent-scope atomics; validated R9/R12 absmax 0.0).
__device__ __forceinline__ void gstore(float* p, float v) {
  __hip_atomic_store(p, v, __ATOMIC_RELAXED, __HIP_MEMORY_SCOPE_AGENT);
}
__device__ __forceinline__ float gload(const float* p) {
  return __hip_atomic_load(p, __ATOMIC_RELAXED, __HIP_MEMORY_SCOPE_AGENT);
}

// Monotonic-counter grid barrier (R12-validated).
__device__ __forceinline__ void gbar(unsigned int* cnt, unsigned int tgt) {
  __syncthreads();
  if (threadIdx.x == 0) {
    __hip_atomic_fetch_add(cnt, 1u, __ATOMIC_ACQ_REL, __HIP_MEMORY_SCOPE_AGENT);
    while (__hip_atomic_load(cnt, __ATOMIC_ACQUIRE, __HIP_MEMORY_SCOPE_AGENT) < tgt) {
      __builtin_amdgcn_s_sleep(4);
    }
  }
  __syncthreads();
}

// seq_lengths: int64 or int32. True values in [128,256], never 0 =>
// little-endian int64 has lens32[1]==0.
__device__ __forceinline__ int read_len(const int* __restrict__ lens, int b) {
  return (lens[1] == 0) ? lens[2 * b] : lens[b];
}

// ---------------------------------------------------------------------------
// Kernel 1: NAIVE fused GAT (proven correct in R8). Only change vs previous
// round: pooled output is written TRANSPOSED as xT[t][c][b] so the LSTM's
// per-step x staging is coalesced (b-minor contiguous).
// ---------------------------------------------------------------------------
__global__ __launch_bounds__(256) void gat_naive(
    const float* __restrict__ feat, const int* __restrict__ lens,
    const float* __restrict__ W1, const float* __restrict__ as1,
    const float* __restrict__ ad1, const float* __restrict__ b1,
    const float* __restrict__ W2, const float* __restrict__ as2,
    const float* __restrict__ ad2, const float* __restrict__ b2,
    float* __restrict__ xT)
{
  const int n = blockIdx.x;
  const int tid = threadIdx.x;
  const int bb = n >> 8;          // batch
  const int tt = n & 255;         // time
  if (tt >= read_len(lens, bb)) { // masked frame: pooled = 0
    if (tid < 128) xT[((size_t)tt * 128 + tid) * 32 + bb] = 0.f;
    return;
  }

  __shared__ float xs[352];       // x [22][16]
  __shared__ float hbuf[2816];    // per-head h [22][128]; later h2 [22][128]
  __shared__ float x2s[11264];    // GAT1 output [22][512] (relu'd)
  __shared__ float asrc[22], adst[22], alpha[484];

  for (int i = tid; i < 352; i += 256) xs[i] = feat[(size_t)n * 352 + i];
  __syncthreads();

  for (int hd = 0; hd < 4; hd++) {
    for (int i = tid; i < 2816; i += 256) {
      int a = i >> 7, c = i & 127;
      float acc = 0.f;
      for (int f = 0; f < 16; f++) acc += xs[a * 16 + f] * W1[f * 512 + hd * 128 + c];
      hbuf[i] = acc;
    }
    __syncthreads();
    if (tid < 44) {
      int a = tid >> 1;
      const float* av = (tid & 1) ? ad1 : as1;
      float s = 0.f;
      for (int c = 0; c < 128; c++) s += hbuf[a * 128 + c] * av[hd * 128 + c];
      ((tid & 1) ? adst : asrc)[a] = s;
    }
    __syncthreads();
    if (tid < 22) {
      float ev[22], m = -1e30f;
      for (int j = 0; j < 22; j++) {
        float e = adst[tid] + asrc[j];
        e = (e > 0.f) ? e : 0.2f * e;
        ev[j] = e; if (e > m) m = e;
      }
      float s = 0.f;
      for (int j = 0; j < 22; j++) { ev[j] = __expf(ev[j] - m); s += ev[j]; }
      float inv = 1.f / s;
      for (int j = 0; j < 22; j++) alpha[tid * 22 + j] = ev[j] * inv;
    }
    __syncthreads();
    for (int i = tid; i < 2816; i += 256) {
      int a = i >> 7, c = i & 127;
      float acc = 0.f;
      for (int j = 0; j < 22; j++) acc += alpha[a * 22 + j] * hbuf[j * 128 + c];
      x2s[a * 512 + hd * 128 + c] = fmaxf(acc + b1[hd * 128 + c], 0.f);
    }
    __syncthreads();
  }

  for (int i = tid; i < 2816; i += 256) {
    int a = i >> 7, c = i & 127;
    float acc = 0.f;
    for (int k = 0; k < 512; k++) acc += x2s[a * 512 + k] * W2[(size_t)k * 128 + c];
    hbuf[i] = acc;
  }
  __syncthreads();
  if (tid < 44) {
    int a = tid >> 1;
    const float* av = (tid & 1) ? ad2 : as2;
    float s = 0.f;
    for (int c = 0; c < 128; c++) s += hbuf[a * 128 + c] * av[c];
    ((tid & 1) ? adst : asrc)[a] = s;
  }
  __syncthreads();
  if (tid < 22) {
    float ev[22], m = -1e30f;
    for (int j = 0; j < 22; j++) {
      float e = adst[tid] + asrc[j];
      e = (e > 0.f) ? e : 0.2f * e;
      ev[j] = e; if (e > m) m = e;
    }
    float s = 0.f;
    for (int j = 0; j < 22; j++) { ev[j] = __expf(ev[j] - m); s += ev[j]; }
    float inv = 1.f / s;
    for (int j = 0; j < 22; j++) alpha[tid * 22 + j] = ev[j] * inv;
  }
  __syncthreads();
  if (tid < 128) {
    float s = 0.f;
    for (int a = 0; a < 22; a++) {
      float v = b2[tid];
      for (int j = 0; j < 22; j++) v += alpha[a * 22 + j] * hbuf[j * 128 + tid];
      s += fmaxf(v, 0.f);
    }
    xT[((size_t)tt * 128 + tid) * 32 + bb] = s * (1.f / 22.f);
  }
}

// ---------------------------------------------------------------------------
// Kernel 2: LDS-resident-weight batch-32 GEMM LSTM.
// 64 blocks x 512 threads. Blocks 0..31: layer 0 (8 j's each); 32..63:
// layer 1 (8 j's each). Each block computes ALL 32 batches for its j-slice:
// per step a [32b x 32col] x K GEMM (K=384 L0 / 512 L1) with weights loaded
// into LDS ONCE (no per-step L2 weight traffic; each LDS weight feeds 8 FMAs).
// Software pipeline + double-buffered transposed agent handoff hT[j][b] and
// one grid barrier per phase are IDENTICAL in structure to the proven R12
// scheme (phase p: L0 step p, L1 step p-1, both consume prv buffers).
// Thread tile: 8 batches x 2 cols, 8-way K-split (k = kp + 8t) reduced via
// in-wave shfl_xor(1,2,4). XOR swizzles:
//   hs[k][b]   stored at k*32 + (b ^ ((k&7)<<2))  -> b128 reads: 8 distinct
//              bank-quads (one per kp) + 8-way same-addr broadcast.
//   wlds[k][c] stored at k*32 + (c ^ ((k&3)<<1)).
// LDS: 64KB weights + 64KB hs + gates = ~132KB (gfx950: 160KB/CU, 1 blk/CU).
// ---------------------------------------------------------------------------
__global__ __launch_bounds__(512) void lstm_pipe(
    const float* __restrict__ xT,
    const float* __restrict__ Wih0, const float* __restrict__ Whh0,
    const float* __restrict__ bih0, const float* __restrict__ bhh0,
    const float* __restrict__ Wih1, const float* __restrict__ Whh1,
    const float* __restrict__ bih1, const float* __restrict__ bhh1,
    const int* __restrict__ lens,
    const float* __restrict__ clfw, const float* __restrict__ clfb,
    float* __restrict__ ws, float* __restrict__ out)
{
  __shared__ float wlds[16384];        // [K][32] swizzled (64 KB)
  __shared__ float hs[16384];          // [K][32] swizzled (64 KB)
  __shared__ float gates[32 * 34 + 2]; // [b][c], pad 34

  unsigned int* cnt = (unsigned int*)ws;
  float* h0T = ws + 64;                // [2][256*32] transposed h0
  float* h1T = ws + 64 + 16384;        // [2][256*32] transposed h1

  const int tid  = threadIdx.x;
  const bool isL1 = blockIdx.x >= 32;
  const int j0   = (isL1 ? (int)blockIdx.x - 32 : (int)blockIdx.x) * 8;
  const int K    = isL1 ? 512 : 384;   // L1: [h0(256); h1(256)]  L0: [x(128); h0(256)]

  // ---- one-time: weights -> LDS (col c = gate*8 + jl) ----
  for (int c = 0; c < 32; c++) {
    const int row = ((c >> 3) << 8) + j0 + (c & 7);
    for (int k = tid; k < K; k += 512) {
      float v;
      if (isL1) v = (k < 256) ? Wih1[row * 256 + k] : Whh1[row * 256 + k - 256];
      else      v = (k < 128) ? Wih0[row * 128 + k] : Whh0[row * 256 + k - 128];
      wlds[k * 32 + (c ^ ((k & 3) << 1))] = v;
    }
  }

  // GEMM thread mapping: kp in-wave (shfl reduce), cg = col pair, bg = wave-pair batch octet
  const int kp = tid & 7;
  const int cg = (tid >> 3) & 15;
  const int bg = tid >> 7;
  const int c0 = cg * 2;
  const int b0 = bg * 8;
  const int nk = K >> 3;               // 48 (L0) / 64 (L1) k-iters, k = kp + 8t
  const float* hp0 = hs   + kp * 32 + ((b0)     ^ (kp << 2));
  const float* hp1 = hs   + kp * 32 + ((b0 + 4) ^ (kp << 2));
  const float* wp  = wlds + kp * 32 + (c0 ^ ((kp & 3) << 1));

  // nonlinearity mapping (tid < 256): thread = (batch nb, local j njl); holds c-state
  const int nb = tid >> 3, njl = tid & 7;
  float bb0 = 0.f, bb1 = 0.f, bb2 = 0.f, bb3 = 0.f;
  int len_b = 256;
  if (tid < 256) {
    const int j = j0 + njl;
    if (isL1) {
      bb0 = bih1[j] + bhh1[j];             bb1 = bih1[256 + j] + bhh1[256 + j];
      bb2 = bih1[512 + j] + bhh1[512 + j]; bb3 = bih1[768 + j] + bhh1[768 + j];
    } else {
      bb0 = bih0[j] + bhh0[j];             bb1 = bih0[256 + j] + bhh0[256 + j];
      bb2 = bih0[512 + j] + bhh0[512 + j]; bb3 = bih0[768 + j] + bhh0[768 + j];
    }
    len_b = read_len(lens, nb);
  }
  float creg = 0.f;

  unsigned int tgt = 0;
  for (int p = 0; p <= T_LEN; p++) {
    const int cur = p & 1, prv = cur ^ 1;

    // ---- stage inputs into hs (coalesced b-minor global, swizzled LDS) ----
    if (isL1) {
      const float* s0 = h0T + prv * 8192;
      const float* s1 = h1T + prv * 8192;
      #pragma unroll 8
      for (int i = tid; i < 16384; i += 512) {
        const int k = i >> 5, b = i & 31;
        const float v = (k < 256) ? gload(s0 + (k << 5) + b)
                                  : gload(s1 + ((k - 256) << 5) + b);
        hs[(k << 5) + (b ^ ((k & 7) << 2))] = v;
      }
    } else {
      const float* s0 = h0T + prv * 8192;
      const float* xp = xT + (size_t)p * 4096;
      #pragma unroll 8
      for (int i = tid; i < 12288; i += 512) {
        const int k = i >> 5, b = i & 31;
        float v;
        if (k < 128) v = (p < T_LEN) ? xp[(k << 5) + b] : 0.f;
        else         v = gload(s0 + ((k - 128) << 5) + b);
        hs[(k << 5) + (b ^ ((k & 7) << 2))] = v;
      }
    }
    __syncthreads();

    const bool compute = isL1 ? (p >= 1) : (p < T_LEN);
    if (compute) {
      // ---- [32b x 32c] x K GEMM, weights+inputs from LDS ----
      float a[2][8] = {{0.f}};
      #pragma unroll 16
      for (int t = 0; t < nk; t++) {
        const float4 hA = *(const float4*)(hp0 + t * 256);
        const float4 hB = *(const float4*)(hp1 + t * 256);
        const float2 wv = *(const float2*)(wp + t * 256);
        a[0][0] += wv.x * hA.x; a[0][1] += wv.x * hA.y;
        a[0][2] += wv.x * hA.z; a[0][3] += wv.x * hA.w;
        a[0][4] += wv.x * hB.x; a[0][5] += wv.x * hB.y;
        a[0][6] += wv.x * hB.z; a[0][7] += wv.x * hB.w;
        a[1][0] += wv.y * hA.x; a[1][1] += wv.y * hA.y;
        a[1][2] += wv.y * hA.z; a[1][3] += wv.y * hA.w;
        a[1][4] += wv.y * hB.x; a[1][5] += wv.y * hB.y;
        a[1][6] += wv.y * hB.z; a[1][7] += wv.y * hB.w;
      }
      // K-split reduce across the 8 kp lanes (in-wave butterfly)
      #pragma unroll
      for (int cc = 0; cc < 2; cc++) {
        #pragma unroll
        for (int i = 0; i < 8; i++) {
          float v = a[cc][i];
          v += __shfl_xor(v, 1);
          v += __shfl_xor(v, 2);
          v += __shfl_xor(v, 4);
          a[cc][i] = v;
        }
      }
      // lane kp publishes batch b0+kp for its col pair (static-index select)
      float g0 = a[0][0], g1 = a[1][0];
      #pragma unroll
      for (int i = 1; i < 8; i++) if (kp == i) { g0 = a[0][i]; g1 = a[1][i]; }
      *(float2*)&gates[(b0 + kp) * 34 + c0] = make_float2(g0, g1);
    }
    __syncthreads();

    if (compute && tid < 256) {
      const float gi = gates[nb * 34 + njl];
      const float gf = gates[nb * 34 + 8 + njl];
      const float gg = gates[nb * 34 + 16 + njl];
      const float go = gates[nb * 34 + 24 + njl];
      const float iv = sigmoidf_(gi + bb0);
      const float fv = sigmoidf_(gf + bb1);
      const float gv = tanhf(gg + bb2);
      const float ov = sigmoidf_(go + bb3);
      const float cnew = fv * creg + iv * gv;
      const float hnew = ov * tanhf(cnew);
      const int t_eff = isL1 ? (p - 1) : p;
      const bool valid = t_eff < len_b;
      // frozen republish past seq len: previous h from staged hs
      const int kold = (isL1 ? 256 : 128) + j0 + njl;
      const float hold = hs[(kold << 5) + (nb ^ ((kold & 7) << 2))];
      const float houtv = valid ? hnew : hold;
      if (valid) creg = cnew;
      float* dst = (isL1 ? h1T : h0T) + cur * 8192 + (j0 + njl) * 32 + nb;
      gstore(dst, houtv);
    }

    tgt += NBLK_SEQ;
    gbar(cnt, tgt);
  }

  // classifier: h1[255] was published at phase 256 into buffer 0.
  if (blockIdx.x == 0) {
    if (tid < 256) {
      const int b = tid & 31, jg = tid >> 5;
      float s = 0.f;
      #pragma unroll 4
      for (int jj = 0; jj < 32; jj++) {
        const int j = jg * 32 + jj;
        s += gload(h1T + j * 32 + b) * clfw[j];
      }
      gates[jg * 32 + b] = s;
    }
    __syncthreads();
    if (tid < 32) {
      float s = clfb[0];
      #pragma unroll
      for (int g = 0; g < 8; g++) s += gates[g * 32 + tid];
      out[tid] = s;
    }
  }
}

// ---------------------------------------------------------------------------
extern "C" void kernel_launch(void* const* d_in, const int* in_sizes, int n_in,
                              void* d_out, int out_size, void* d_ws, size_t ws_size,
                              hipStream_t stream) {
  (void)in_sizes; (void)n_in; (void)out_size; (void)ws_size;
  const float* feat = (const float*)d_in[0];
  const int*   lens = (const int*)d_in[1];
  const float* W1   = (const float*)d_in[2];
  const float* as1  = (const float*)d_in[3];
  const float* ad1  = (const float*)d_in[4];
  const float* b1   = (const float*)d_in[5];
  const float* W2   = (const float*)d_in[6];
  const float* as2  = (const float*)d_in[7];
  const float* ad2  = (const float*)d_in[8];
  const float* b2   = (const float*)d_in[9];
  const float* Wih0 = (const float*)d_in[10];
  const float* Whh0 = (const float*)d_in[11];
  const float* bih0 = (const float*)d_in[12];
  const float* bhh0 = (const float*)d_in[13];
  const float* Wih1 = (const float*)d_in[14];
  const float* Whh1 = (const float*)d_in[15];
  const float* bih1 = (const float*)d_in[16];
  const float* bhh1 = (const float*)d_in[17];
  const float* clfw = (const float*)d_in[18];
  const float* clfb = (const float*)d_in[19];

  float* ws  = (float*)d_ws;
  float* xT  = ws + 64 + 32768;   // [256 t][128 c][32 b] = 4 MB
  float* outp = (float*)d_out;

  // zero barrier counter + h0/h1 double buffers (cnt 64 + 2*8192 + 2*8192)
  hipMemsetAsync(d_ws, 0, (64 + 32768) * sizeof(float), stream);

  gat_naive<<<8192, 256, 0, stream>>>(feat, lens, W1, as1, ad1, b1,
                                      W2, as2, ad2, b2, xT);

  void* args[] = {
    (void*)&xT,
    (void*)&Wih0, (void*)&Whh0, (void*)&bih0, (void*)&bhh0,
    (void*)&Wih1, (void*)&Whh1, (void*)&bih1, (void*)&bhh1,
    (void*)&lens, (void*)&clfw, (void*)&clfb, (void*)&ws, (void*)&outp
  };
  hipLaunchCooperativeKernel((const void*)lstm_pipe, dim3(NBLK_SEQ), dim3(512),
                             args, 0, stream);
}

// Round 3
// 4738.254 us; speedup vs baseline: 2.1293x; 1.3318x over previous
//
#include <hip/hip_runtime.h>
#include <math.h>

#define A_PL 22
#define F_IN_ 16
#define T_LEN 256
#define NBLK_SEQ 64

typedef unsigned long long ull;

__device__ __forceinline__ float sigmoidf_(float x) { return 1.f / (1.f + __expf(-x)); }

// Cross-XCD-safe handoff (per-op agent-scope atomics; validated R9/R12 absmax 0.0).
__device__ __forceinline__ void gstore(float* p, float v) {
  __hip_atomic_store(p, v, __ATOMIC_RELAXED, __HIP_MEMORY_SCOPE_AGENT);
}
__device__ __forceinline__ float gload(const float* p) {
  return __hip_atomic_load(p, __ATOMIC_RELAXED, __HIP_MEMORY_SCOPE_AGENT);
}
__device__ __forceinline__ ull gload8(const ull* p) {
  return __hip_atomic_load(p, __ATOMIC_RELAXED, __HIP_MEMORY_SCOPE_AGENT);
}

// Distributed flag barrier: block i release-stores its own 128B-strided flag;
// wave 0 polls all 64 flags (lane = flag) with acquire + s_sleep(1).
// Replaces the contended single-counter RMW (R1: 64 serialized agent RMWs/phase).
__device__ __forceinline__ void gbar_flags(unsigned* arr, int bid, unsigned tgt) {
  __syncthreads();
  if (threadIdx.x == 0) {
    __hip_atomic_store(arr + bid * 32, tgt, __ATOMIC_RELEASE, __HIP_MEMORY_SCOPE_AGENT);
  }
  if (threadIdx.x < 64) {
    while (__hip_atomic_load(arr + threadIdx.x * 32, __ATOMIC_ACQUIRE,
                             __HIP_MEMORY_SCOPE_AGENT) < tgt) {
      __builtin_amdgcn_s_sleep(1);
    }
  }
  __syncthreads();
}

// seq_lengths: int64 or int32. True values in [128,256], never 0 =>
// little-endian int64 has lens32[1]==0.
__device__ __forceinline__ int read_len(const int* __restrict__ lens, int b) {
  return (lens[1] == 0) ? lens[2 * b] : lens[b];
}

// ---------------------------------------------------------------------------
// Kernel 1: NAIVE fused GAT (proven correct in R8; unchanged this round).
// pooled output written TRANSPOSED as xT[t][c][b] for coalesced LSTM staging.
// ---------------------------------------------------------------------------
__global__ __launch_bounds__(256) void gat_naive(
    const float* __restrict__ feat, const int* __restrict__ lens,
    const float* __restrict__ W1, const float* __restrict__ as1,
    const float* __restrict__ ad1, const float* __restrict__ b1,
    const float* __restrict__ W2, const float* __restrict__ as2,
    const float* __restrict__ ad2, const float* __restrict__ b2,
    float* __restrict__ xT)
{
  const int n = blockIdx.x;
  const int tid = threadIdx.x;
  const int bb = n >> 8;          // batch
  const int tt = n & 255;         // time
  if (tt >= read_len(lens, bb)) { // masked frame: pooled = 0
    if (tid < 128) xT[((size_t)tt * 128 + tid) * 32 + bb] = 0.f;
    return;
  }

  __shared__ float xs[352];       // x [22][16]
  __shared__ float hbuf[2816];    // per-head h [22][128]; later h2 [22][128]
  __shared__ float x2s[11264];    // GAT1 output [22][512] (relu'd)
  __shared__ float asrc[22], adst[22], alpha[484];

  for (int i = tid; i < 352; i += 256) xs[i] = feat[(size_t)n * 352 + i];
  __syncthreads();

  for (int hd = 0; hd < 4; hd++) {
    for (int i = tid; i < 2816; i += 256) {
      int a = i >> 7, c = i & 127;
      float acc = 0.f;
      for (int f = 0; f < 16; f++) acc += xs[a * 16 + f] * W1[f * 512 + hd * 128 + c];
      hbuf[i] = acc;
    }
    __syncthreads();
    if (tid < 44) {
      int a = tid >> 1;
      const float* av = (tid & 1) ? ad1 : as1;
      float s = 0.f;
      for (int c = 0; c < 128; c++) s += hbuf[a * 128 + c] * av[hd * 128 + c];
      ((tid & 1) ? adst : asrc)[a] = s;
    }
    __syncthreads();
    if (tid < 22) {
      float ev[22], m = -1e30f;
      for (int j = 0; j < 22; j++) {
        float e = adst[tid] + asrc[j];
        e = (e > 0.f) ? e : 0.2f * e;
        ev[j] = e; if (e > m) m = e;
      }
      float s = 0.f;
      for (int j = 0; j < 22; j++) { ev[j] = __expf(ev[j] - m); s += ev[j]; }
      float inv = 1.f / s;
      for (int j = 0; j < 22; j++) alpha[tid * 22 + j] = ev[j] * inv;
    }
    __syncthreads();
    for (int i = tid; i < 2816; i += 256) {
      int a = i >> 7, c = i & 127;
      float acc = 0.f;
      for (int j = 0; j < 22; j++) acc += alpha[a * 22 + j] * hbuf[j * 128 + c];
      x2s[a * 512 + hd * 128 + c] = fmaxf(acc + b1[hd * 128 + c], 0.f);
    }
    __syncthreads();
  }

  for (int i = tid; i < 2816; i += 256) {
    int a = i >> 7, c = i & 127;
    float acc = 0.f;
    for (int k = 0; k < 512; k++) acc += x2s[a * 512 + k] * W2[(size_t)k * 128 + c];
    hbuf[i] = acc;
  }
  __syncthreads();
  if (tid < 44) {
    int a = tid >> 1;
    const float* av = (tid & 1) ? ad2 : as2;
    float s = 0.f;
    for (int c = 0; c < 128; c++) s += hbuf[a * 128 + c] * av[c];
    ((tid & 1) ? adst : asrc)[a] = s;
  }
  __syncthreads();
  if (tid < 22) {
    float ev[22], m = -1e30f;
    for (int j = 0; j < 22; j++) {
      float e = adst[tid] + asrc[j];
      e = (e > 0.f) ? e : 0.2f * e;
      ev[j] = e; if (e > m) m = e;
    }
    float s = 0.f;
    for (int j = 0; j < 22; j++) { ev[j] = __expf(ev[j] - m); s += ev[j]; }
    float inv = 1.f / s;
    for (int j = 0; j < 22; j++) alpha[tid * 22 + j] = ev[j] * inv;
  }
  __syncthreads();
  if (tid < 128) {
    float s = 0.f;
    for (int a = 0; a < 22; a++) {
      float v = b2[tid];
      for (int j = 0; j < 22; j++) v += alpha[a * 22 + j] * hbuf[j * 128 + tid];
      s += fmaxf(v, 0.f);
    }
    xT[((size_t)tt * 128 + tid) * 32 + bb] = s * (1.f / 22.f);
  }
}

// ---------------------------------------------------------------------------
// Kernel 2: register-resident-weight batch-32 GEMM LSTM.
// Proven pipeline (64 blocks: 32 L0 + 32 L1; phase p computes L0 step p and
// L1 step p-1; double-buffered transposed agent handoff hT[j][b]; one grid
// barrier per phase; mask-freeze republish). R3 retile:
//   thread = (kp 0..15, cg 0..7, bg 0..3): c-tile 4, b-tile 8, 16-way K-split
//   (k = kp + 16t). 32 FMA per 32B LDS h-read (2x R2 intensity). Weights in
//   registers wr[4][NK] (L1: 128 VGPR), statically indexed. Butterfly reduce
//   via shfl_xor(1,2,4,8); lane kp publishes (c0+(kp&3), b0+(kp>>2)) and +4.
// hs[k][b] swizzle: k*32 + (b ^ ((k&7)<<2)) -> b128 reads 2-way aliased max.
// ---------------------------------------------------------------------------
template<int KK>
__device__ __forceinline__ void lstm_body(
    const int j0, const float* __restrict__ xT,
    const float* __restrict__ Wih, const float* __restrict__ Whh,
    const float* __restrict__ bih, const float* __restrict__ bhh,
    const int* __restrict__ lens,
    float* __restrict__ h0T, float* __restrict__ h1T,
    unsigned* __restrict__ arr, const int bid,
    float* __restrict__ hs, float* __restrict__ gates)
{
  constexpr int NK = KK / 16;           // 24 (L0) / 32 (L1)
  constexpr bool L1 = (KK == 512);
  const int tid = threadIdx.x;
  const int kp = tid & 15;
  const int cg = (tid >> 4) & 7;
  const int bg = tid >> 7;
  const int c0 = cg * 4;
  const int b0 = bg * 8;
  const int sw = (kp & 7) << 2;
  const float* hpA = hs + kp * 32 + (b0 ^ sw);
  const float* hpB = hs + kp * 32 + ((b0 + 4) ^ sw);

  // ---- one-time: weight slice -> registers (col c = gate*8 + jl) ----
  float wr[4][NK];
  {
    const int r0 = ((c0 >> 3) << 8) + j0 + (c0 & 7);   // c0..c0+3 same gate
    #pragma unroll
    for (int ci = 0; ci < 4; ci++) {
      const int r = r0 + ci;
      #pragma unroll
      for (int t = 0; t < NK; t++) {
        const int k = kp + 16 * t;
        if (L1) wr[ci][t] = (k < 256) ? Wih[r * 256 + k] : Whh[r * 256 + k - 256];
        else    wr[ci][t] = (k < 128) ? Wih[r * 128 + k] : Whh[r * 256 + k - 128];
      }
    }
  }

  // nonlinearity mapping (tid < 256): thread = (batch nb, local j njl)
  const int nb = tid >> 3, njl = tid & 7;
  float bb0 = 0.f, bb1 = 0.f, bb2 = 0.f, bb3 = 0.f;
  int len_b = T_LEN;
  if (tid < 256) {
    const int j = j0 + njl;
    bb0 = bih[j]       + bhh[j];
    bb1 = bih[256 + j] + bhh[256 + j];
    bb2 = bih[512 + j] + bhh[512 + j];
    bb3 = bih[768 + j] + bhh[768 + j];
    len_b = read_len(lens, nb);
  }
  float creg = 0.f;

  for (int p = 0; p <= T_LEN; p++) {
    const int cur = p & 1, prv = cur ^ 1;
    const bool compute = L1 ? (p >= 1) : (p < T_LEN);

    if (compute) {
      // ---- stage inputs into hs (8B atomic handoff, float4 xT) ----
      if (L1) {
        const ull* s0 = (const ull*)(h0T + prv * 8192);
        const ull* s1 = (const ull*)(h1T + prv * 8192);
        #pragma unroll
        for (int i = tid; i < 8192; i += 512) {       // 512 rows x 16 ull
          const int k = i >> 4, e = i & 15;
          const ull v = (k < 256) ? gload8(s0 + (k << 4) + e)
                                  : gload8(s1 + ((k - 256) << 4) + e);
          *(ull*)(hs + (k << 5) + ((e << 1) ^ ((k & 7) << 2))) = v;
        }
      } else {
        const float* xp = xT + (size_t)p * 4096;
        #pragma unroll
        for (int i = tid; i < 1024; i += 512) {       // 128 rows x 8 float4
          const int k = i >> 3, b4 = (i & 7) << 2;
          const float4 v = *(const float4*)(xp + (k << 5) + b4);
          *(float4*)(hs + (k << 5) + (b4 ^ ((k & 7) << 2))) = v;
        }
        const ull* s0 = (const ull*)(h0T + prv * 8192);
        #pragma unroll
        for (int i = tid; i < 4096; i += 512) {       // 256 rows x 16 ull
          const int k = 128 + (i >> 4), e = i & 15;
          const ull v = gload8(s0 + ((k - 128) << 4) + e);
          *(ull*)(hs + (k << 5) + ((e << 1) ^ ((k & 7) << 2))) = v;
        }
      }
      __syncthreads();

      // ---- [32b x 32c] x K GEMM: weights in regs, h from LDS ----
      float a[4][8] = {};
      #pragma unroll
      for (int t = 0; t < NK; t++) {
        const float4 hA = *(const float4*)(hpA + t * 512);  // 16 rows = 512 fl
        const float4 hB = *(const float4*)(hpB + t * 512);
        #pragma unroll
        for (int ci = 0; ci < 4; ci++) {
          const float w = wr[ci][t];
          a[ci][0] += w * hA.x; a[ci][1] += w * hA.y;
          a[ci][2] += w * hA.z; a[ci][3] += w * hA.w;
          a[ci][4] += w * hB.x; a[ci][5] += w * hB.y;
          a[ci][6] += w * hB.z; a[ci][7] += w * hB.w;
        }
      }
      // K-split reduce across the 16 kp lanes (in-wave butterfly)
      #pragma unroll
      for (int ci = 0; ci < 4; ci++) {
        #pragma unroll
        for (int bi = 0; bi < 8; bi++) {
          float v = a[ci][bi];
          v += __shfl_xor(v, 1);
          v += __shfl_xor(v, 2);
          v += __shfl_xor(v, 4);
          v += __shfl_xor(v, 8);
          a[ci][bi] = v;
        }
      }
      // lane kp publishes (c0+(kp&3), b0+(kp>>2)) and (.., b0+4+(kp>>2))
      float g0 = 0.f, g1 = 0.f;
      #pragma unroll
      for (int ci = 0; ci < 4; ci++) {
        #pragma unroll
        for (int bq = 0; bq < 4; bq++) {
          if ((kp & 3) == ci && (kp >> 2) == bq) { g0 = a[ci][bq]; g1 = a[ci][bq + 4]; }
        }
      }
      gates[(b0 + (kp >> 2)) * 34 + c0 + (kp & 3)] = g0;
      gates[(b0 + 4 + (kp >> 2)) * 34 + c0 + (kp & 3)] = g1;
      __syncthreads();

      if (tid < 256) {
        const float gi = gates[nb * 34 + njl];
        const float gf = gates[nb * 34 + 8 + njl];
        const float gg = gates[nb * 34 + 16 + njl];
        const float go = gates[nb * 34 + 24 + njl];
        const float iv = sigmoidf_(gi + bb0);
        const float fv = sigmoidf_(gf + bb1);
        const float gv = tanhf(gg + bb2);
        const float ov = sigmoidf_(go + bb3);
        const float cnew = fv * creg + iv * gv;
        const float hnew = ov * tanhf(cnew);
        const int t_eff = L1 ? (p - 1) : p;
        const bool valid = t_eff < len_b;
        // frozen republish past seq len: previous h from staged hs
        const int kold = (L1 ? 256 : 128) + j0 + njl;
        const float hold = hs[(kold << 5) + (nb ^ ((kold & 7) << 2))];
        const float houtv = valid ? hnew : hold;
        if (valid) creg = cnew;
        gstore((L1 ? h1T : h0T) + cur * 8192 + (j0 + njl) * 32 + nb, houtv);
      }
    }

    gbar_flags(arr, bid, (unsigned)(p + 1));
  }
}

__global__ __launch_bounds__(512) void lstm_pipe(
    const float* __restrict__ xT,
    const float* __restrict__ Wih0, const float* __restrict__ Whh0,
    const float* __restrict__ bih0, const float* __restrict__ bhh0,
    const float* __restrict__ Wih1, const float* __restrict__ Whh1,
    const float* __restrict__ bih1, const float* __restrict__ bhh1,
    const int* __restrict__ lens,
    const float* __restrict__ clfw, const float* __restrict__ clfb,
    float* __restrict__ ws, float* __restrict__ out)
{
  __shared__ float hs[16384];          // [K][32] swizzled (64 KB)
  __shared__ float gates[32 * 34 + 2]; // [b][c], pad 34

  unsigned* arr = (unsigned*)ws;       // flag array: 64 x 128B stride
  float* h0T = ws + 2048;              // [2][256*32] transposed h0
  float* h1T = ws + 2048 + 16384;      // [2][256*32] transposed h1

  const int bid = blockIdx.x;
  if (bid >= 32)
    lstm_body<512>((bid - 32) * 8, xT, Wih1, Whh1, bih1, bhh1, lens,
                   h0T, h1T, arr, bid, hs, gates);
  else
    lstm_body<384>(bid * 8, xT, Wih0, Whh0, bih0, bhh0, lens,
                   h0T, h1T, arr, bid, hs, gates);

  // classifier: h1[255] was published at phase 256 into buffer 0.
  if (bid == 0) {
    const int tid = threadIdx.x;
    if (tid < 256) {
      const int b = tid & 31, jg = tid >> 5;
      float s = 0.f;
      #pragma unroll 8
      for (int jj = 0; jj < 32; jj++) {
        const int j = jg * 32 + jj;
        s += gload(h1T + j * 32 + b) * clfw[j];
      }
      gates[jg * 32 + b] = s;
    }
    __syncthreads();
    if (tid < 32) {
      float s = clfb[0];
      #pragma unroll
      for (int g = 0; g < 8; g++) s += gates[g * 32 + tid];
      out[tid] = s;
    }
  }
}

// ---------------------------------------------------------------------------
extern "C" void kernel_launch(void* const* d_in, const int* in_sizes, int n_in,
                              void* d_out, int out_size, void* d_ws, size_t ws_size,
                              hipStream_t stream) {
  (void)in_sizes; (void)n_in; (void)out_size; (void)ws_size;
  const float* feat = (const float*)d_in[0];
  const int*   lens = (const int*)d_in[1];
  const float* W1   = (const float*)d_in[2];
  const float* as1  = (const float*)d_in[3];
  const float* ad1  = (const float*)d_in[4];
  const float* b1   = (const float*)d_in[5];
  const float* W2   = (const float*)d_in[6];
  const float* as2  = (const float*)d_in[7];
  const float* ad2  = (const float*)d_in[8];
  const float* b2   = (const float*)d_in[9];
  const float* Wih0 = (const float*)d_in[10];
  const float* Whh0 = (const float*)d_in[11];
  const float* bih0 = (const float*)d_in[12];
  const float* bhh0 = (const float*)d_in[13];
  const float* Wih1 = (const float*)d_in[14];
  const float* Whh1 = (const float*)d_in[15];
  const float* bih1 = (const float*)d_in[16];
  const float* bhh1 = (const float*)d_in[17];
  const float* clfw = (const float*)d_in[18];
  const float* clfb = (const float*)d_in[19];

  float* ws  = (float*)d_ws;
  float* xT  = ws + 2048 + 32768;   // [256 t][128 c][32 b] = 4 MB
  float* outp = (float*)d_out;

  // zero barrier flags + h0/h1 double buffers
  hipMemsetAsync(d_ws, 0, (2048 + 32768) * sizeof(float), stream);

  gat_naive<<<8192, 256, 0, stream>>>(feat, lens, W1, as1, ad1, b1,
                                      W2, as2, ad2, b2, xT);

  void* args[] = {
    (void*)&xT,
    (void*)&Wih0, (void*)&Whh0, (void*)&bih0, (void*)&bhh0,
    (void*)&Wih1, (void*)&Whh1, (void*)&bih1, (void*)&bhh1,
    (void*)&lens, (void*)&clfw, (void*)&clfb, (void*)&ws, (void*)&outp
  };
  hipLaunchCooperativeKernel((const void*)lstm_pipe, dim3(NBLK_SEQ), dim3(512),
                             args, 0, stream);
}

// Round 4
// 3628.873 us; speedup vs baseline: 2.7802x; 1.3057x over previous
//
#include <hip/hip_runtime.h>
#include <math.h>

#define A_PL 22
#define F_IN_ 16
#define T_LEN 256
#define NBLK_SEQ 64

typedef unsigned long long ull;

__device__ __forceinline__ float sigmoidf_(float x) { return 1.f / (1.f + __expf(-x)); }

// Cross-XCD-safe handoff (per-op agent-scope atomics; validated R9/R12 absmax 0.0).
__device__ __forceinline__ void gstore(float* p, float v) {
  __hip_atomic_store(p, v, __ATOMIC_RELAXED, __HIP_MEMORY_SCOPE_AGENT);
}
__device__ __forceinline__ float gload(const float* p) {
  return __hip_atomic_load(p, __ATOMIC_RELAXED, __HIP_MEMORY_SCOPE_AGENT);
}

// Dataflow wait: lanes 0..31 poll L0 flags to tgt_lo, lanes 32..63 poll L1
// flags to tgt_hi. Acquire-poll + explicit agent-acquire fence (L1 inval)
// so subsequent PLAIN vector loads see the released data.
__device__ __forceinline__ void dwait(unsigned* arr, int tlo, int thi) {
  if (threadIdx.x < 64) {
    const int lane = threadIdx.x;
    int t = (lane < 32) ? tlo : thi;
    if (t < 0) t = 0;
    const unsigned tu = (unsigned)t;
    while (__hip_atomic_load(arr + lane * 32, __ATOMIC_ACQUIRE,
                             __HIP_MEMORY_SCOPE_AGENT) < tu) {
      __builtin_amdgcn_s_sleep(1);
    }
  }
  __syncthreads();
  __builtin_amdgcn_fence(__ATOMIC_ACQUIRE, "agent");
}

// DPP quad_perm butterfly stages (VALU pipe, not LDS): xor1 = [1,0,3,2],
// xor2 = [2,3,0,1].
__device__ __forceinline__ float dpp_xor1(float v) {
  int r = __builtin_amdgcn_mov_dpp(__builtin_bit_cast(int, v), 0xB1, 0xF, 0xF, true);
  return __builtin_bit_cast(float, r);
}
__device__ __forceinline__ float dpp_xor2(float v) {
  int r = __builtin_amdgcn_mov_dpp(__builtin_bit_cast(int, v), 0x4E, 0xF, 0xF, true);
  return __builtin_bit_cast(float, r);
}

// seq_lengths: int64 or int32. True values in [128,256], never 0 =>
// little-endian int64 has lens32[1]==0.
__device__ __forceinline__ int read_len(const int* __restrict__ lens, int b) {
  return (lens[1] == 0) ? lens[2 * b] : lens[b];
}

// ---------------------------------------------------------------------------
// Kernel 1: fused GAT. R4: GAT1 h-loop hoists W1 into 16 regs + float4 xs;
// W2 matmul hoists the coalesced W2 column stream across the 11 per-thread
// outputs with float4 x2s broadcasts. All other stages unchanged (R8-proven).
// Output written TRANSPOSED as xT[t][c][b].
// ---------------------------------------------------------------------------
__global__ __launch_bounds__(256) void gat_naive(
    const float* __restrict__ feat, const int* __restrict__ lens,
    const float* __restrict__ W1, const float* __restrict__ as1,
    const float* __restrict__ ad1, const float* __restrict__ b1,
    const float* __restrict__ W2, const float* __restrict__ as2,
    const float* __restrict__ ad2, const float* __restrict__ b2,
    float* __restrict__ xT)
{
  const int n = blockIdx.x;
  const int tid = threadIdx.x;
  const int bb = n >> 8;          // batch
  const int tt = n & 255;         // time
  if (tt >= read_len(lens, bb)) { // masked frame: pooled = 0
    if (tid < 128) xT[((size_t)tt * 128 + tid) * 32 + bb] = 0.f;
    return;
  }

  __shared__ float xs[352];       // x [22][16]
  __shared__ float hbuf[2816];    // per-head h [22][128]; later h2 [22][128]
  __shared__ float x2s[11264];    // GAT1 output [22][512] (relu'd)
  __shared__ float asrc[22], adst[22], alpha[484];

  for (int i = tid; i < 352; i += 256) xs[i] = feat[(size_t)n * 352 + i];
  __syncthreads();

  const int c_ = tid & 127;
  const int ap_ = tid >> 7;       // a-parity for this thread

  for (int hd = 0; hd < 4; hd++) {
    {
      float wreg[16];
      #pragma unroll
      for (int f = 0; f < 16; f++) wreg[f] = W1[f * 512 + hd * 128 + c_];
      #pragma unroll
      for (int q = 0; q < 11; q++) {
        const int a = ap_ + 2 * q;
        float acc = 0.f;
        #pragma unroll
        for (int f4 = 0; f4 < 4; f4++) {
          const float4 x4 = *(const float4*)(xs + a * 16 + f4 * 4);
          acc += x4.x * wreg[f4 * 4] + x4.y * wreg[f4 * 4 + 1]
               + x4.z * wreg[f4 * 4 + 2] + x4.w * wreg[f4 * 4 + 3];
        }
        hbuf[a * 128 + c_] = acc;
      }
    }
    __syncthreads();
    if (tid < 44) {
      int a = tid >> 1;
      const float* av = (tid & 1) ? ad1 : as1;
      float s = 0.f;
      for (int c = 0; c < 128; c++) s += hbuf[a * 128 + c] * av[hd * 128 + c];
      ((tid & 1) ? adst : asrc)[a] = s;
    }
    __syncthreads();
    if (tid < 22) {
      float ev[22], m = -1e30f;
      for (int j = 0; j < 22; j++) {
        float e = adst[tid] + asrc[j];
        e = (e > 0.f) ? e : 0.2f * e;
        ev[j] = e; if (e > m) m = e;
      }
      float s = 0.f;
      for (int j = 0; j < 22; j++) { ev[j] = __expf(ev[j] - m); s += ev[j]; }
      float inv = 1.f / s;
      for (int j = 0; j < 22; j++) alpha[tid * 22 + j] = ev[j] * inv;
    }
    __syncthreads();
    for (int i = tid; i < 2816; i += 256) {
      int a = i >> 7, c = i & 127;
      float acc = 0.f;
      for (int j = 0; j < 22; j++) acc += alpha[a * 22 + j] * hbuf[j * 128 + c];
      x2s[a * 512 + hd * 128 + c] = fmaxf(acc + b1[hd * 128 + c], 0.f);
    }
    __syncthreads();
  }

  // ---- W2 matmul: hbuf = relu-in of GAT2 h = x2s @ W2 ----
  {
    float acc[11];
    #pragma unroll
    for (int q = 0; q < 11; q++) acc[q] = 0.f;
    for (int k = 0; k < 512; k += 4) {
      const float w0 = W2[(size_t)(k + 0) * 128 + c_];
      const float w1 = W2[(size_t)(k + 1) * 128 + c_];
      const float w2 = W2[(size_t)(k + 2) * 128 + c_];
      const float w3 = W2[(size_t)(k + 3) * 128 + c_];
      #pragma unroll
      for (int q = 0; q < 11; q++) {
        const float4 x4 = *(const float4*)(x2s + (ap_ + 2 * q) * 512 + k);
        acc[q] += x4.x * w0 + x4.y * w1 + x4.z * w2 + x4.w * w3;
      }
    }
    #pragma unroll
    for (int q = 0; q < 11; q++) hbuf[(ap_ + 2 * q) * 128 + c_] = acc[q];
  }
  __syncthreads();
  if (tid < 44) {
    int a = tid >> 1;
    const float* av = (tid & 1) ? ad2 : as2;
    float s = 0.f;
    for (int c = 0; c < 128; c++) s += hbuf[a * 128 + c] * av[c];
    ((tid & 1) ? adst : asrc)[a] = s;
  }
  __syncthreads();
  if (tid < 22) {
    float ev[22], m = -1e30f;
    for (int j = 0; j < 22; j++) {
      float e = adst[tid] + asrc[j];
      e = (e > 0.f) ? e : 0.2f * e;
      ev[j] = e; if (e > m) m = e;
    }
    float s = 0.f;
    for (int j = 0; j < 22; j++) { ev[j] = __expf(ev[j] - m); s += ev[j]; }
    float inv = 1.f / s;
    for (int j = 0; j < 22; j++) alpha[tid * 22 + j] = ev[j] * inv;
  }
  __syncthreads();
  if (tid < 128) {
    float s = 0.f;
    for (int a = 0; a < 22; a++) {
      float v = b2[tid];
      for (int j = 0; j < 22; j++) v += alpha[a * 22 + j] * hbuf[j * 128 + tid];
      s += fmaxf(v, 0.f);
    }
    xT[((size_t)tt * 128 + tid) * 32 + bb] = s * (1.f / 22.f);
  }
}

// ---------------------------------------------------------------------------
// Kernel 2: register-resident-weight batch-32 GEMM LSTM with DATAFLOW sync.
// 64 blocks (32 L0 + 32 L1), R3 tiling (kp16/cg8/bg4: c-tile 4, b-tile 8,
// 16-way K-split). h0/h1 handoff QUAD-buffered (step s -> buf[s&3]) with
// per-block monotonic flags:
//   L0@p: waits L0 flags >= p (h0[p-1] producers), L1 flags >= p-2
//         (anti-overwrite of h0[p-4]; quad buffer). Computes step p.
//   L1@p: waits ALL flags >= p (h0[p-1] + h1[p-2] producers). Computes
//         step p-1. L0 runs up to 2 phases ahead -> no cross-layer convoy.
// Flag release AFTER __syncthreads (vmcnt drained) = R3-validated discipline.
// Staging via plain float4 (dwait's acquire fence invalidates L1 first).
// Butterfly xor1/xor2 on DPP (VALU), xor4/xor8 via shfl.
// ---------------------------------------------------------------------------
template<int KK>
__device__ __forceinline__ void lstm_body(
    const int j0, const float* __restrict__ xT,
    const float* __restrict__ Wih, const float* __restrict__ Whh,
    const float* __restrict__ bih, const float* __restrict__ bhh,
    const int* __restrict__ lens,
    float* __restrict__ h0T, float* __restrict__ h1T,
    unsigned* __restrict__ arr, const int bid,
    float* __restrict__ hs, float* __restrict__ gates)
{
  constexpr int NK = KK / 16;           // 24 (L0) / 32 (L1)
  constexpr bool IS1 = (KK == 512);
  const int tid = threadIdx.x;
  const int kp = tid & 15;
  const int cg = (tid >> 4) & 7;
  const int bg = tid >> 7;
  const int c0 = cg * 4;
  const int b0 = bg * 8;
  const int sw = (kp & 7) << 2;
  const float* hpA = hs + kp * 32 + (b0 ^ sw);
  const float* hpB = hs + kp * 32 + ((b0 + 4) ^ sw);

  // ---- one-time: weight slice -> registers (col c = gate*8 + jl) ----
  float wr[4][NK];
  {
    const int r0 = ((c0 >> 3) << 8) + j0 + (c0 & 7);   // c0..c0+3 same gate
    #pragma unroll
    for (int ci = 0; ci < 4; ci++) {
      const int r = r0 + ci;
      #pragma unroll
      for (int t = 0; t < NK; t++) {
        const int k = kp + 16 * t;
        if (IS1) wr[ci][t] = (k < 256) ? Wih[r * 256 + k] : Whh[r * 256 + k - 256];
        else     wr[ci][t] = (k < 128) ? Wih[r * 128 + k] : Whh[r * 256 + k - 128];
      }
    }
  }

  // nonlinearity mapping (tid < 256): thread = (batch nb, local j njl)
  const int nb = tid >> 3, njl = tid & 7;
  float bb0 = 0.f, bb1 = 0.f, bb2 = 0.f, bb3 = 0.f;
  int len_b = T_LEN;
  if (tid < 256) {
    const int j = j0 + njl;
    bb0 = bih[j]       + bhh[j];
    bb1 = bih[256 + j] + bhh[256 + j];
    bb2 = bih[512 + j] + bhh[512 + j];
    bb3 = bih[768 + j] + bhh[768 + j];
    len_b = read_len(lens, nb);
  }
  float creg = 0.f;

  const int PMAX = IS1 ? T_LEN : (T_LEN - 1);
  for (int p = 0; p <= PMAX; p++) {
    if (p > 0) dwait(arr, p, IS1 ? p : p - 2);
    const bool compute = IS1 ? (p >= 1) : true;

    if (compute) {
      // ---- stage inputs into hs (plain float4; swizzled LDS writes) ----
      if (IS1) {
        const float* s0 = h0T + (size_t)((p - 1) & 3) * 8192;
        const float* s1 = h1T + (size_t)((p + 2) & 3) * 8192;  // (p-2)&3
        #pragma unroll
        for (int i = tid; i < 4096; i += 512) {
          const int k = i >> 3, b4 = (i & 7) << 2;
          const float4 v = (k < 256)
              ? *(const float4*)(s0 + (k << 5) + b4)
              : *(const float4*)(s1 + ((k - 256) << 5) + b4);
          *(float4*)(hs + (k << 5) + (b4 ^ ((k & 7) << 2))) = v;
        }
      } else {
        const float* xp = xT + (size_t)p * 4096;
        const float* s0 = h0T + (size_t)((p + 3) & 3) * 8192;  // (p-1)&3
        #pragma unroll
        for (int i = tid; i < 3072; i += 512) {
          const int k = i >> 3, b4 = (i & 7) << 2;
          const float4 v = (k < 128)
              ? *(const float4*)(xp + (k << 5) + b4)
              : *(const float4*)(s0 + ((k - 128) << 5) + b4);
          *(float4*)(hs + (k << 5) + (b4 ^ ((k & 7) << 2))) = v;
        }
      }
      __syncthreads();

      // ---- [32b x 32c] x K GEMM: weights in regs, h from LDS ----
      float a[4][8] = {};
      #pragma unroll
      for (int t = 0; t < NK; t++) {
        const float4 hA = *(const float4*)(hpA + t * 512);
        const float4 hB = *(const float4*)(hpB + t * 512);
        #pragma unroll
        for (int ci = 0; ci < 4; ci++) {
          const float w = wr[ci][t];
          a[ci][0] += w * hA.x; a[ci][1] += w * hA.y;
          a[ci][2] += w * hA.z; a[ci][3] += w * hA.w;
          a[ci][4] += w * hB.x; a[ci][5] += w * hB.y;
          a[ci][6] += w * hB.z; a[ci][7] += w * hB.w;
        }
      }
      // K-split reduce across 16 kp lanes: xor1/xor2 on DPP, xor4/8 via shfl
      #pragma unroll
      for (int ci = 0; ci < 4; ci++) {
        #pragma unroll
        for (int bi = 0; bi < 8; bi++) {
          float v = a[ci][bi];
          v += dpp_xor1(v);
          v += dpp_xor2(v);
          v += __shfl_xor(v, 4);
          v += __shfl_xor(v, 8);
          a[ci][bi] = v;
        }
      }
      // lane kp publishes (c0+(kp&3), b0+(kp>>2)) and (.., b0+4+(kp>>2))
      float g0 = 0.f, g1 = 0.f;
      #pragma unroll
      for (int ci = 0; ci < 4; ci++) {
        #pragma unroll
        for (int bq = 0; bq < 4; bq++) {
          if ((kp & 3) == ci && (kp >> 2) == bq) { g0 = a[ci][bq]; g1 = a[ci][bq + 4]; }
        }
      }
      gates[(b0 + (kp >> 2)) * 34 + c0 + (kp & 3)] = g0;
      gates[(b0 + 4 + (kp >> 2)) * 34 + c0 + (kp & 3)] = g1;
      __syncthreads();

      if (tid < 256) {
        const float gi = gates[nb * 34 + njl];
        const float gf = gates[nb * 34 + 8 + njl];
        const float gg = gates[nb * 34 + 16 + njl];
        const float go = gates[nb * 34 + 24 + njl];
        const float iv = sigmoidf_(gi + bb0);
        const float fv = sigmoidf_(gf + bb1);
        const float gv = tanhf(gg + bb2);
        const float ov = sigmoidf_(go + bb3);
        const float cnew = fv * creg + iv * gv;
        const float hnew = ov * tanhf(cnew);
        const int t_eff = IS1 ? (p - 1) : p;
        const bool valid = t_eff < len_b;
        // frozen republish past seq len: previous h from staged hs
        const int kold = (IS1 ? 256 : 128) + j0 + njl;
        const float hold = hs[(kold << 5) + (nb ^ ((kold & 7) << 2))];
        const float houtv = valid ? hnew : hold;
        if (valid) creg = cnew;
        float* dst = (IS1 ? h1T + (size_t)((p + 3) & 3) * 8192    // (p-1)&3
                          : h0T + (size_t)(p & 3) * 8192)
                     + (j0 + njl) * 32 + nb;
        gstore(dst, houtv);
      }
    }

    __syncthreads();   // drain all waves' stores before the release
    if (tid == 0)
      __hip_atomic_store(arr + bid * 32, (unsigned)(p + 1), __ATOMIC_RELEASE,
                         __HIP_MEMORY_SCOPE_AGENT);
  }
}

__global__ __launch_bounds__(512, 2) void lstm_pipe(
    const float* __restrict__ xT,
    const float* __restrict__ Wih0, const float* __restrict__ Whh0,
    const float* __restrict__ bih0, const float* __restrict__ bhh0,
    const float* __restrict__ Wih1, const float* __restrict__ Whh1,
    const float* __restrict__ bih1, const float* __restrict__ bhh1,
    const int* __restrict__ lens,
    const float* __restrict__ clfw, const float* __restrict__ clfb,
    float* __restrict__ ws, float* __restrict__ out)
{
  __shared__ float hs[16384];          // [K][32] swizzled (64 KB)
  __shared__ float gates[32 * 34 + 2]; // [b][c], pad 34

  unsigned* arr = (unsigned*)ws;       // flag array: 64 x 128B stride
  float* h0T = ws + 2048;              // [4][256*32] quad-buffered h0
  float* h1T = ws + 2048 + 32768;      // [4][256*32] quad-buffered h1

  const int bid = blockIdx.x;
  if (bid >= 32)
    lstm_body<512>((bid - 32) * 8, xT, Wih1, Whh1, bih1, bhh1, lens,
                   h0T, h1T, arr, bid, hs, gates);
  else
    lstm_body<384>(bid * 8, xT, Wih0, Whh0, bih0, bhh0, lens,
                   h0T, h1T, arr, bid, hs, gates);

  // classifier: h1[255] lives in buf[255&3] = 3, published at L1 phase 256.
  if (bid == 0) {
    const int tid = threadIdx.x;
    dwait(arr, 0, T_LEN + 1);          // all L1 flags >= 257
    const float* h1f = h1T + (size_t)3 * 8192;
    if (tid < 256) {
      const int b = tid & 31, jg = tid >> 5;
      float s = 0.f;
      #pragma unroll 8
      for (int jj = 0; jj < 32; jj++) {
        const int j = jg * 32 + jj;
        s += gload(h1f + j * 32 + b) * clfw[j];
      }
      gates[jg * 32 + b] = s;
    }
    __syncthreads();
    if (tid < 32) {
      float s = clfb[0];
      #pragma unroll
      for (int g = 0; g < 8; g++) s += gates[g * 32 + tid];
      out[tid] = s;
    }
  }
}

// ---------------------------------------------------------------------------
extern "C" void kernel_launch(void* const* d_in, const int* in_sizes, int n_in,
                              void* d_out, int out_size, void* d_ws, size_t ws_size,
                              hipStream_t stream) {
  (void)in_sizes; (void)n_in; (void)out_size; (void)ws_size;
  const float* feat = (const float*)d_in[0];
  const int*   lens = (const int*)d_in[1];
  const float* W1   = (const float*)d_in[2];
  const float* as1  = (const float*)d_in[3];
  const float* ad1  = (const float*)d_in[4];
  const float* b1   = (const float*)d_in[5];
  const float* W2   = (const float*)d_in[6];
  const float* as2  = (const float*)d_in[7];
  const float* ad2  = (const float*)d_in[8];
  const float* b2   = (const float*)d_in[9];
  const float* Wih0 = (const float*)d_in[10];
  const float* Whh0 = (const float*)d_in[11];
  const float* bih0 = (const float*)d_in[12];
  const float* bhh0 = (const float*)d_in[13];
  const float* Wih1 = (const float*)d_in[14];
  const float* Whh1 = (const float*)d_in[15];
  const float* bih1 = (const float*)d_in[16];
  const float* bhh1 = (const float*)d_in[17];
  const float* clfw = (const float*)d_in[18];
  const float* clfb = (const float*)d_in[19];

  float* ws  = (float*)d_ws;
  float* xT  = ws + 2048 + 65536;   // [256 t][128 c][32 b] = 4 MB
  float* outp = (float*)d_out;

  // zero barrier flags + h0/h1 quad buffers (2048 + 2*4*8192 floats)
  hipMemsetAsync(d_ws, 0, (2048 + 65536) * sizeof(float), stream);

  gat_naive<<<8192, 256, 0, stream>>>(feat, lens, W1, as1, ad1, b1,
                                      W2, as2, ad2, b2, xT);

  void* args[] = {
    (void*)&xT,
    (void*)&Wih0, (void*)&Whh0, (void*)&bih0, (void*)&bhh0,
    (void*)&Wih1, (void*)&Whh1, (void*)&bih1, (void*)&bhh1,
    (void*)&lens, (void*)&clfw, (void*)&clfb, (void*)&ws, (void*)&outp
  };
  hipLaunchCooperativeKernel((const void*)lstm_pipe, dim3(NBLK_SEQ), dim3(512),
                             args, 0, stream);
}

// Round 6
// 3589.027 us; speedup vs baseline: 2.8111x; 1.0111x over previous
//
#include <hip/hip_runtime.h>
#include <math.h>

#define A_PL 22
#define F_IN_ 16
#define T_LEN 256
#define NBLK_SEQ 64

__device__ __forceinline__ float sigmoidf_(float x) { return 1.f / (1.f + __expf(-x)); }

// Cross-XCD-safe handoff (per-op agent-scope atomics; validated R9/R12 absmax 0.0).
__device__ __forceinline__ void gstore(float* p, float v) {
  __hip_atomic_store(p, v, __ATOMIC_RELAXED, __HIP_MEMORY_SCOPE_AGENT);
}
__device__ __forceinline__ float gload(const float* p) {
  return __hip_atomic_load(p, __ATOMIC_RELAXED, __HIP_MEMORY_SCOPE_AGENT);
}

// Dataflow wait: lanes 0..31 poll L0 flags to tgt_lo, lanes 32..63 poll L1
// flags to tgt_hi. Acquire-poll + explicit agent-acquire fence (L1 inval)
// so subsequent PLAIN vector loads see the released data. (R4-validated.)
__device__ __forceinline__ void dwait(unsigned* arr, int tlo, int thi) {
  if (threadIdx.x < 64) {
    const int lane = threadIdx.x;
    int t = (lane < 32) ? tlo : thi;
    if (t < 0) t = 0;
    const unsigned tu = (unsigned)t;
    while (__hip_atomic_load(arr + lane * 32, __ATOMIC_ACQUIRE,
                             __HIP_MEMORY_SCOPE_AGENT) < tu) {
      __builtin_amdgcn_s_sleep(1);
    }
  }
  __syncthreads();
  __builtin_amdgcn_fence(__ATOMIC_ACQUIRE, "agent");
}

// DPP quad_perm butterfly stages (VALU pipe, not LDS): xor1 = [1,0,3,2],
// xor2 = [2,3,0,1]. (R4-validated.)
__device__ __forceinline__ float dpp_xor1(float v) {
  int r = __builtin_amdgcn_mov_dpp(__builtin_bit_cast(int, v), 0xB1, 0xF, 0xF, true);
  return __builtin_bit_cast(float, r);
}
__device__ __forceinline__ float dpp_xor2(float v) {
  int r = __builtin_amdgcn_mov_dpp(__builtin_bit_cast(int, v), 0x4E, 0xF, 0xF, true);
  return __builtin_bit_cast(float, r);
}

// seq_lengths: int64 or int32. True values in [128,256], never 0 =>
// little-endian int64 has lens32[1]==0.
__device__ __forceinline__ int read_len(const int* __restrict__ lens, int b) {
  return (lens[1] == 0) ? lens[2 * b] : lens[b];
}

// ---------------------------------------------------------------------------
// Kernel 1: fused GAT (R4 version, passed; unchanged this round).
// Output written TRANSPOSED as xT[t][c][b].
// ---------------------------------------------------------------------------
__global__ __launch_bounds__(256) void gat_naive(
    const float* __restrict__ feat, const int* __restrict__ lens,
    const float* __restrict__ W1, const float* __restrict__ as1,
    const float* __restrict__ ad1, const float* __restrict__ b1,
    const float* __restrict__ W2, const float* __restrict__ as2,
    const float* __restrict__ ad2, const float* __restrict__ b2,
    float* __restrict__ xT)
{
  const int n = blockIdx.x;
  const int tid = threadIdx.x;
  const int bb = n >> 8;          // batch
  const int tt = n & 255;         // time
  if (tt >= read_len(lens, bb)) { // masked frame: pooled = 0
    if (tid < 128) xT[((size_t)tt * 128 + tid) * 32 + bb] = 0.f;
    return;
  }

  __shared__ float xs[352];       // x [22][16]
  __shared__ float hbuf[2816];    // per-head h [22][128]; later h2 [22][128]
  __shared__ float x2s[11264];    // GAT1 output [22][512] (relu'd)
  __shared__ float asrc[22], adst[22], alpha[484];

  for (int i = tid; i < 352; i += 256) xs[i] = feat[(size_t)n * 352 + i];
  __syncthreads();

  const int c_ = tid & 127;
  const int ap_ = tid >> 7;       // a-parity for this thread

  for (int hd = 0; hd < 4; hd++) {
    {
      float wreg[16];
      #pragma unroll
      for (int f = 0; f < 16; f++) wreg[f] = W1[f * 512 + hd * 128 + c_];
      #pragma unroll
      for (int q = 0; q < 11; q++) {
        const int a = ap_ + 2 * q;
        float acc = 0.f;
        #pragma unroll
        for (int f4 = 0; f4 < 4; f4++) {
          const float4 x4 = *(const float4*)(xs + a * 16 + f4 * 4);
          acc += x4.x * wreg[f4 * 4] + x4.y * wreg[f4 * 4 + 1]
               + x4.z * wreg[f4 * 4 + 2] + x4.w * wreg[f4 * 4 + 3];
        }
        hbuf[a * 128 + c_] = acc;
      }
    }
    __syncthreads();
    if (tid < 44) {
      int a = tid >> 1;
      const float* av = (tid & 1) ? ad1 : as1;
      float s = 0.f;
      for (int c = 0; c < 128; c++) s += hbuf[a * 128 + c] * av[hd * 128 + c];
      ((tid & 1) ? adst : asrc)[a] = s;
    }
    __syncthreads();
    if (tid < 22) {
      float ev[22], m = -1e30f;
      for (int j = 0; j < 22; j++) {
        float e = adst[tid] + asrc[j];
        e = (e > 0.f) ? e : 0.2f * e;
        ev[j] = e; if (e > m) m = e;
      }
      float s = 0.f;
      for (int j = 0; j < 22; j++) { ev[j] = __expf(ev[j] - m); s += ev[j]; }
      float inv = 1.f / s;
      for (int j = 0; j < 22; j++) alpha[tid * 22 + j] = ev[j] * inv;
    }
    __syncthreads();
    for (int i = tid; i < 2816; i += 256) {
      int a = i >> 7, c = i & 127;
      float acc = 0.f;
      for (int j = 0; j < 22; j++) acc += alpha[a * 22 + j] * hbuf[j * 128 + c];
      x2s[a * 512 + hd * 128 + c] = fmaxf(acc + b1[hd * 128 + c], 0.f);
    }
    __syncthreads();
  }

  // ---- W2 matmul: hbuf = relu-in of GAT2 h = x2s @ W2 ----
  {
    float acc[11];
    #pragma unroll
    for (int q = 0; q < 11; q++) acc[q] = 0.f;
    for (int k = 0; k < 512; k += 4) {
      const float w0 = W2[(size_t)(k + 0) * 128 + c_];
      const float w1 = W2[(size_t)(k + 1) * 128 + c_];
      const float w2 = W2[(size_t)(k + 2) * 128 + c_];
      const float w3 = W2[(size_t)(k + 3) * 128 + c_];
      #pragma unroll
      for (int q = 0; q < 11; q++) {
        const float4 x4 = *(const float4*)(x2s + (ap_ + 2 * q) * 512 + k);
        acc[q] += x4.x * w0 + x4.y * w1 + x4.z * w2 + x4.w * w3;
      }
    }
    #pragma unroll
    for (int q = 0; q < 11; q++) hbuf[(ap_ + 2 * q) * 128 + c_] = acc[q];
  }
  __syncthreads();
  if (tid < 44) {
    int a = tid >> 1;
    const float* av = (tid & 1) ? ad2 : as2;
    float s = 0.f;
    for (int c = 0; c < 128; c++) s += hbuf[a * 128 + c] * av[c];
    ((tid & 1) ? adst : asrc)[a] = s;
  }
  __syncthreads();
  if (tid < 22) {
    float ev[22], m = -1e30f;
    for (int j = 0; j < 22; j++) {
      float e = adst[tid] + asrc[j];
      e = (e > 0.f) ? e : 0.2f * e;
      ev[j] = e; if (e > m) m = e;
    }
    float s = 0.f;
    for (int j = 0; j < 22; j++) { ev[j] = __expf(ev[j] - m); s += ev[j]; }
    float inv = 1.f / s;
    for (int j = 0; j < 22; j++) alpha[tid * 22 + j] = ev[j] * inv;
  }
  __syncthreads();
  if (tid < 128) {
    float s = 0.f;
    for (int a = 0; a < 22; a++) {
      float v = b2[tid];
      for (int j = 0; j < 22; j++) v += alpha[a * 22 + j] * hbuf[j * 128 + tid];
      s += fmaxf(v, 0.f);
    }
    xT[((size_t)tt * 128 + tid) * 32 + bb] = s * (1.f / 22.f);
  }
}

// ---------------------------------------------------------------------------
// Kernel 2: register-resident-weight batch-32 GEMM LSTM with DATAFLOW sync.
// == R4 kernel (passed, 2691us, absmax 0.0) + ONE change: the weight
// registers wr[4][NK] are PINNED via an opaque asm no-op after the one-time
// load, so the compiler cannot rematerialize the global weight loads inside
// the phase loop (R4 measured VGPR_Count=112 < 128 needed => weights were
// re-streamed from L3 every phase, ~3-4us/phase).
// Tiling (R3-proven): thread = (kp 0..15, cg 0..7, bg 0..3): c-tile 4,
// b-tile 8, 16-way K-split. Quad-buffered h0T/h1T agent handoff; per-block
// monotonic flags; L0@p waits {L0>=p, L1>=p-2}; L1@p waits {all>=p};
// release after __syncthreads. Butterfly xor1/xor2 on DPP, xor4/8 via shfl.
// ---------------------------------------------------------------------------
template<int KK>
__device__ __forceinline__ void lstm_body(
    const int j0, const float* __restrict__ xT,
    const float* __restrict__ Wih, const float* __restrict__ Whh,
    const float* __restrict__ bih, const float* __restrict__ bhh,
    const int* __restrict__ lens,
    float* __restrict__ h0T, float* __restrict__ h1T,
    unsigned* __restrict__ arr, const int bid,
    float* __restrict__ hs, float* __restrict__ gates)
{
  constexpr int NK = KK / 16;           // 24 (L0) / 32 (L1)
  constexpr bool IS1 = (KK == 512);
  const int tid = threadIdx.x;
  const int kp = tid & 15;
  const int cg = (tid >> 4) & 7;
  const int bg = tid >> 7;
  const int c0 = cg * 4;
  const int b0 = bg * 8;
  const int sw = (kp & 7) << 2;
  const float* hpA = hs + kp * 32 + (b0 ^ sw);
  const float* hpB = hs + kp * 32 + ((b0 + 4) ^ sw);

  // ---- one-time: weight slice -> registers (col c = gate*8 + jl) ----
  float wr[4][NK];
  {
    const int r0 = ((c0 >> 3) << 8) + j0 + (c0 & 7);   // c0..c0+3 same gate
    #pragma unroll
    for (int ci = 0; ci < 4; ci++) {
      const int r = r0 + ci;
      #pragma unroll
      for (int t = 0; t < NK; t++) {
        const int k = kp + 16 * t;
        if (IS1) wr[ci][t] = (k < 256) ? Wih[r * 256 + k] : Whh[r * 256 + k - 256];
        else     wr[ci][t] = (k < 128) ? Wih[r * 128 + k] : Whh[r * 256 + k - 128];
      }
    }
  }
  // PIN: opaque asm makes each weight the output of an unknowable op ->
  // rematerialization of the global load is illegal; values stay in VGPRs.
  #pragma unroll
  for (int ci = 0; ci < 4; ci++) {
    #pragma unroll
    for (int t = 0; t < NK; t++) {
      asm volatile("" : "+v"(wr[ci][t]));
    }
  }

  // nonlinearity mapping (tid < 256): thread = (batch nb, local j njl)
  const int nb = tid >> 3, njl = tid & 7;
  float bb0 = 0.f, bb1 = 0.f, bb2 = 0.f, bb3 = 0.f;
  int len_b = T_LEN;
  if (tid < 256) {
    const int j = j0 + njl;
    bb0 = bih[j]       + bhh[j];
    bb1 = bih[256 + j] + bhh[256 + j];
    bb2 = bih[512 + j] + bhh[512 + j];
    bb3 = bih[768 + j] + bhh[768 + j];
    len_b = read_len(lens, nb);
  }
  float creg = 0.f;

  const int PMAX = IS1 ? T_LEN : (T_LEN - 1);
  for (int p = 0; p <= PMAX; p++) {
    if (p > 0) dwait(arr, p, IS1 ? p : p - 2);
    const bool compute = IS1 ? (p >= 1) : true;

    if (compute) {
      // ---- stage inputs into hs (plain float4; swizzled LDS writes) ----
      if (IS1) {
        const float* s0 = h0T + (size_t)((p - 1) & 3) * 8192;
        const float* s1 = h1T + (size_t)((p + 2) & 3) * 8192;  // (p-2)&3
        #pragma unroll
        for (int i = tid; i < 4096; i += 512) {
          const int k = i >> 3, b4 = (i & 7) << 2;
          const float4 v = (k < 256)
              ? *(const float4*)(s0 + (k << 5) + b4)
              : *(const float4*)(s1 + ((k - 256) << 5) + b4);
          *(float4*)(hs + (k << 5) + (b4 ^ ((k & 7) << 2))) = v;
        }
      } else {
        const float* xp = xT + (size_t)p * 4096;
        const float* s0 = h0T + (size_t)((p + 3) & 3) * 8192;  // (p-1)&3
        #pragma unroll
        for (int i = tid; i < 3072; i += 512) {
          const int k = i >> 3, b4 = (i & 7) << 2;
          const float4 v = (k < 128)
              ? *(const float4*)(xp + (k << 5) + b4)
              : *(const float4*)(s0 + ((k - 128) << 5) + b4);
          *(float4*)(hs + (k << 5) + (b4 ^ ((k & 7) << 2))) = v;
        }
      }
      __syncthreads();

      // ---- [32b x 32c] x K GEMM: weights in regs, h from LDS ----
      float a[4][8] = {};
      #pragma unroll
      for (int t = 0; t < NK; t++) {
        const float4 hA = *(const float4*)(hpA + t * 512);
        const float4 hB = *(const float4*)(hpB + t * 512);
        #pragma unroll
        for (int ci = 0; ci < 4; ci++) {
          const float w = wr[ci][t];
          a[ci][0] += w * hA.x; a[ci][1] += w * hA.y;
          a[ci][2] += w * hA.z; a[ci][3] += w * hA.w;
          a[ci][4] += w * hB.x; a[ci][5] += w * hB.y;
          a[ci][6] += w * hB.z; a[ci][7] += w * hB.w;
        }
      }
      // K-split reduce across 16 kp lanes: xor1/xor2 on DPP, xor4/8 via shfl
      #pragma unroll
      for (int ci = 0; ci < 4; ci++) {
        #pragma unroll
        for (int bi = 0; bi < 8; bi++) {
          float v = a[ci][bi];
          v += dpp_xor1(v);
          v += dpp_xor2(v);
          v += __shfl_xor(v, 4);
          v += __shfl_xor(v, 8);
          a[ci][bi] = v;
        }
      }
      // lane kp publishes (c0+(kp&3), b0+(kp>>2)) and (.., b0+4+(kp>>2))
      float g0 = 0.f, g1 = 0.f;
      #pragma unroll
      for (int ci = 0; ci < 4; ci++) {
        #pragma unroll
        for (int bq = 0; bq < 4; bq++) {
          if ((kp & 3) == ci && (kp >> 2) == bq) { g0 = a[ci][bq]; g1 = a[ci][bq + 4]; }
        }
      }
      gates[(b0 + (kp >> 2)) * 34 + c0 + (kp & 3)] = g0;
      gates[(b0 + 4 + (kp >> 2)) * 34 + c0 + (kp & 3)] = g1;
      __syncthreads();

      if (tid < 256) {
        const float gi = gates[nb * 34 + njl];
        const float gf = gates[nb * 34 + 8 + njl];
        const float gg = gates[nb * 34 + 16 + njl];
        const float go = gates[nb * 34 + 24 + njl];
        const float iv = sigmoidf_(gi + bb0);
        const float fv = sigmoidf_(gf + bb1);
        const float gv = tanhf(gg + bb2);
        const float ov = sigmoidf_(go + bb3);
        const float cnew = fv * creg + iv * gv;
        const float hnew = ov * tanhf(cnew);
        const int t_eff = IS1 ? (p - 1) : p;
        const bool valid = t_eff < len_b;
        // frozen republish past seq len: previous h from staged hs
        const int kold = (IS1 ? 256 : 128) + j0 + njl;
        const float hold = hs[(kold << 5) + (nb ^ ((kold & 7) << 2))];
        const float houtv = valid ? hnew : hold;
        if (valid) creg = cnew;
        float* dst = (IS1 ? h1T + (size_t)((p + 3) & 3) * 8192    // (p-1)&3
                          : h0T + (size_t)(p & 3) * 8192)
                     + (j0 + njl) * 32 + nb;
        gstore(dst, houtv);
      }
    }

    __syncthreads();   // drain all waves' stores before the release
    if (tid == 0)
      __hip_atomic_store(arr + bid * 32, (unsigned)(p + 1), __ATOMIC_RELEASE,
                         __HIP_MEMORY_SCOPE_AGENT);
  }
}

__global__ __launch_bounds__(512, 2) void lstm_pipe(
    const float* __restrict__ xT,
    const float* __restrict__ Wih0, const float* __restrict__ Whh0,
    const float* __restrict__ bih0, const float* __restrict__ bhh0,
    const float* __restrict__ Wih1, const float* __restrict__ Whh1,
    const float* __restrict__ bih1, const float* __restrict__ bhh1,
    const int* __restrict__ lens,
    const float* __restrict__ clfw, const float* __restrict__ clfb,
    float* __restrict__ ws, float* __restrict__ out)
{
  __shared__ float hs[16384];          // [K][32] swizzled (64 KB)
  __shared__ float gates[32 * 34 + 2]; // [b][c], pad 34

  unsigned* arr = (unsigned*)ws;       // flag array: 64 x 128B stride
  float* h0T = ws + 2048;              // [4][256*32] quad-buffered h0
  float* h1T = ws + 2048 + 32768;      // [4][256*32] quad-buffered h1

  const int bid = blockIdx.x;
  if (bid >= 32)
    lstm_body<512>((bid - 32) * 8, xT, Wih1, Whh1, bih1, bhh1, lens,
                   h0T, h1T, arr, bid, hs, gates);
  else
    lstm_body<384>(bid * 8, xT, Wih0, Whh0, bih0, bhh0, lens,
                   h0T, h1T, arr, bid, hs, gates);

  // classifier: h1[255] lives in buf[255&3] = 3, published at L1 phase 256.
  if (bid == 0) {
    const int tid = threadIdx.x;
    dwait(arr, 0, T_LEN + 1);          // all L1 flags >= 257
    const float* h1f = h1T + (size_t)3 * 8192;
    if (tid < 256) {
      const int b = tid & 31, jg = tid >> 5;
      float s = 0.f;
      #pragma unroll 8
      for (int jj = 0; jj < 32; jj++) {
        const int j = jg * 32 + jj;
        s += gload(h1f + j * 32 + b) * clfw[j];
      }
      gates[jg * 32 + b] = s;
    }
    __syncthreads();
    if (tid < 32) {
      float s = clfb[0];
      #pragma unroll
      for (int g = 0; g < 8; g++) s += gates[g * 32 + tid];
      out[tid] = s;
    }
  }
}

// ---------------------------------------------------------------------------
extern "C" void kernel_launch(void* const* d_in, const int* in_sizes, int n_in,
                              void* d_out, int out_size, void* d_ws, size_t ws_size,
                              hipStream_t stream) {
  (void)in_sizes; (void)n_in; (void)out_size; (void)ws_size;
  const float* feat = (const float*)d_in[0];
  const int*   lens = (const int*)d_in[1];
  const float* W1   = (const float*)d_in[2];
  const float* as1  = (const float*)d_in[3];
  const float* ad1  = (const float*)d_in[4];
  const float* b1   = (const float*)d_in[5];
  const float* W2   = (const float*)d_in[6];
  const float* as2  = (const float*)d_in[7];
  const float* ad2  = (const float*)d_in[8];
  const float* b2   = (const float*)d_in[9];
  const float* Wih0 = (const float*)d_in[10];
  const float* Whh0 = (const float*)d_in[11];
  const float* bih0 = (const float*)d_in[12];
  const float* bhh0 = (const float*)d_in[13];
  const float* Wih1 = (const float*)d_in[14];
  const float* Whh1 = (const float*)d_in[15];
  const float* bih1 = (const float*)d_in[16];
  const float* bhh1 = (const float*)d_in[17];
  const float* clfw = (const float*)d_in[18];
  const float* clfb = (const float*)d_in[19];

  float* ws  = (float*)d_ws;
  float* xT  = ws + 2048 + 65536;   // [256 t][128 c][32 b] = 4 MB
  float* outp = (float*)d_out;

  // zero barrier flags + h0/h1 quad buffers (2048 + 2*4*8192 floats)
  hipMemsetAsync(d_ws, 0, (2048 + 65536) * sizeof(float), stream);

  gat_naive<<<8192, 256, 0, stream>>>(feat, lens, W1, as1, ad1, b1,
                                      W2, as2, ad2, b2, xT);

  void* args[] = {
    (void*)&xT,
    (void*)&Wih0, (void*)&Whh0, (void*)&bih0, (void*)&bhh0,
    (void*)&Wih1, (void*)&Whh1, (void*)&bih1, (void*)&bhh1,
    (void*)&lens, (void*)&clfw, (void*)&clfb, (void*)&ws, (void*)&outp
  };
  hipLaunchCooperativeKernel((const void*)lstm_pipe, dim3(NBLK_SEQ), dim3(512),
                             args, 0, stream);
}